// Round 1
// baseline (1017.649 us; speedup 1.0000x reference)
//
#include <hip/hip_runtime.h>

// Balanced sinkhorn, persistent kernel, round 6.
// R5 post-mortem: 88% of time is stall; 48 serial cross-block allreduces at
// ~8-9us each dominate. The 2-stage reducer tree (publish -> flag poll ->
// 16 reducers read 1MB -> LDS fold -> replicated fin -> value poll) is ~5
// global round trips deep. R6 collapses it to a single-stage device fp64
// atomic reduction (~3 RTs):
//   - thread t: unsafeAtomicAdd(acc[ph][t], partial)   (HW global_atomic_add_f64)
//   - __syncthreads() drains vmcnt (all block RMWs acked at coherence point)
//   - t0 bumps cnt[ph]; polls cnt[ph]==256; barrier; all threads read sums.
// Each phase gets a fresh pre-zeroed slot (48 of 64) => no parity, sentinel,
// or reset logic. 64B padding per (ph,k) slot spreads RMWs across L3 banks.
// Phase math / LDS tiles / replicated optimizer identical to R3-R5
// (validated, absmax 2.4e-4).

namespace {

constexpr int KDIM = 256;
constexpr int NBLK = 256;   // 1 block/CU, all co-resident (LDS-forced)
constexpr int ROWS = 64;    // rows per block
constexpr float L2E20 = 28.853900817779268f;  // 20 * log2(e)

// ws layout (doubles):
//   acc[64 ph][256 k][8 dbl pad]   131072 dbl (1 MB); val0 at +0, val1 at +1
//   cnt[64 ph][16 u32 pad]         4 KB
constexpr int NPH = 64;        // 48 used
constexpr int SLOT_DBL = 8;    // 64 B per (ph,k) slot
constexpr size_t ACC_DBL = (size_t)NPH * KDIM * SLOT_DBL;  // 131072
constexpr size_t CNT_OFF_DBL = ACC_DBL;
constexpr int CNT_STRIDE = 16; // u32 stride (64 B)
constexpr int CNT_U32 = NPH * CNT_STRIDE;

__device__ __forceinline__ double fast_exp_d(double x) {
  const double LOG2E  = 1.4426950408889634074;
  const double LN2_HI = 6.93147180369123816490e-01;
  const double LN2_LO = 1.90821492927058770002e-10;
  double n = rint(x * LOG2E);
  double t = fma(-n, LN2_HI, x);
  t = fma(-n, LN2_LO, t);
  double p = 2.4801587301587302e-05;
  p = fma(p, t, 1.9841269841269841e-04);
  p = fma(p, t, 1.3888888888888889e-03);
  p = fma(p, t, 8.3333333333333333e-03);
  p = fma(p, t, 4.1666666666666664e-02);
  p = fma(p, t, 1.6666666666666666e-01);
  p = fma(p, t, 0.5);
  p = fma(p, t, 1.0);
  p = fma(p, t, 1.0);
  long long ni = (long long)n;
  double s = __longlong_as_double((unsigned long long)(ni + 1023LL) << 52);
  return p * s;
}

__device__ __forceinline__ double wave_sum_d(double v) {
#pragma unroll
  for (int o = 32; o > 0; o >>= 1) v += __shfl_down(v, o);
  return v;
}
__device__ __forceinline__ double wave_max_d(double v) {
#pragma unroll
  for (int o = 32; o > 0; o >>= 1) v = fmax(v, __shfl_down(v, o));
  return v;
}

__device__ __forceinline__ double pload(const double* p) {
  return __hip_atomic_load(p, __ATOMIC_RELAXED, __HIP_MEMORY_SCOPE_AGENT);
}

}  // namespace

// ---------------------------------------------------------------------------
__global__ __launch_bounds__(256) void kInitWS(double* __restrict__ ws) {
  size_t gid = (size_t)blockIdx.x * 256 + threadIdx.x;
  size_t stride = (size_t)gridDim.x * 256;
  for (size_t j = gid; j < ACC_DBL; j += stride) ws[j] = 0.0;
  unsigned* c = (unsigned*)(ws + CNT_OFF_DBL);
  for (size_t j = gid; j < (size_t)CNT_U32; j += stride) c[j] = 0u;
}

// ---------------------------------------------------------------------------
__global__ __launch_bounds__(256, 1) void sink_main(
    const float* __restrict__ feat, const float* __restrict__ w_in,
    float* __restrict__ out, double* __restrict__ ws) {
  __shared__ float  Et[ROWS * KDIM];   // 64 KB
  __shared__ float  Ft[ROWS * KDIM];   // 64 KB
  __shared__ double alpha[KDIM];
  __shared__ double v1s[ROWS], v2s[ROWS], v3s[ROWS];
  __shared__ double grow[ROWS], wrow[ROWS], sbr[ROWS];
  __shared__ float  mrow[ROWS];
  __shared__ double sred[8];

  const int t = threadIdx.x, bid = blockIdx.x;
  const int wv = t >> 6, lane = t & 63;
  const int b0 = bid * ROWS;

  double* acc = ws;
  unsigned* cnt = (unsigned*)(ws + CNT_OFF_DBL);

  auto blk_sum = [&](double v) -> double {
    v = wave_sum_d(v);
    __syncthreads();
    if (lane == 0) sred[wv] = v;
    __syncthreads();
    return sred[0] + sred[1] + sred[2] + sred[3];
  };
  auto blk_max = [&](double v) -> double {
    v = wave_max_d(v);
    __syncthreads();
    if (lane == 0) sred[wv + 4] = v;
    __syncthreads();
    return fmax(fmax(sred[4], sred[5]), fmax(sred[6], sred[7]));
  };

  // ---- allreduce over blocks for k=0..255 (optionally a value pair per k).
  // Thread t contributes pa(,pb) for k=t; summed result lands in r1(,r2).
  auto allreduce = [&](unsigned ph, bool pair, double pa, double pb,
                       double& r1, double& r2) {
    double* slot = acc + ((size_t)ph * KDIM + t) * SLOT_DBL;
    unsafeAtomicAdd(slot, pa);
    if (pair) unsafeAtomicAdd(slot + 1, pb);
    asm volatile("s_waitcnt vmcnt(0)" ::: "memory");
    __syncthreads();  // all waves drained: block's RMWs are at the L3
    if (t == 0) {
      unsigned* c = cnt + (size_t)ph * CNT_STRIDE;
      unsigned prev = __hip_atomic_fetch_add(c, 1u, __ATOMIC_RELAXED,
                                             __HIP_MEMORY_SCOPE_AGENT);
      if (prev != NBLK - 1) {
        while (__hip_atomic_load(c, __ATOMIC_RELAXED,
                                 __HIP_MEMORY_SCOPE_AGENT) < NBLK)
          __builtin_amdgcn_s_sleep(2);
      }
    }
    __syncthreads();
    r1 = pload(slot);
    if (pair) r2 = pload(slot + 1);
  };

  auto row_pass = [&](double* dstv) {
    double a0 = alpha[4 * lane + 0], a1 = alpha[4 * lane + 1];
    double a2 = alpha[4 * lane + 2], a3 = alpha[4 * lane + 3];
#pragma unroll 4
    for (int r = wv; r < ROWS; r += 4) {
      float4 e4 = ((const float4*)(Et + r * KDIM))[lane];
      double s1 = a0 * (double)e4.x + a1 * (double)e4.y +
                  a2 * (double)e4.z + a3 * (double)e4.w;
      s1 = wave_sum_d(s1);
      if (lane == 0) dstv[r] = s1;
    }
  };
  auto col_partial = [&]() -> double {
    double a = 0.0;
#pragma unroll 8
    for (int r = 0; r < ROWS; ++r) a += (double)Et[r * KDIM + t] * wrow[r];
    return a;
  };

  // ================= setup =================
  {
    const float4* src = (const float4*)(feat + (size_t)b0 * KDIM);
    float4* dst = (float4*)Ft;
#pragma unroll
    for (int s = 0; s < 16; ++s) dst[s * 256 + t] = src[s * 256 + t];
  }
  __syncthreads();
  for (int r = wv; r < ROWS; r += 4) {
    float4 f4 = ((const float4*)(Ft + r * KDIM))[lane];
    float m = fmaxf(fmaxf(f4.x, f4.y), fmaxf(f4.z, f4.w));
#pragma unroll
    for (int o = 32; o > 0; o >>= 1) m = fmaxf(m, __shfl_down(m, o));
    if (lane == 0) {
      mrow[r] = m;
      sbr[r] = fast_exp_d(20.0 * (double)m);
    }
  }
  __syncthreads();
  double pu0 = 0.0;
#pragma unroll 8
  for (int r = 0; r < ROWS; ++r) {
    float e = exp2f((Ft[r * KDIM + t] - mrow[r]) * L2E20);
    Et[r * KDIM + t] = e;
    pu0 += (double)e * sbr[r];
  }
  float w_t = w_in[t], buf_t = 0.0f;
  double k2_t;
  {
    double x = (double)w_t;
    double m = blk_max(x);
    double e = fast_exp_d(x - m);
    double s = blk_sum(e);
    k2_t = e / s;
  }
  unsigned ph = 0;
  double u0_t, dmy;
  allreduce(ph, false, pu0, 0.0, u0_t, dmy);

  // ================= outer loop =================
  for (int it = 0; it < 10; ++it) {
    double u1_t, u2_t;

    // ---- A: v1~, allreduce u1
    alpha[t] = k2_t / u0_t;
    __syncthreads();
    row_pass(v1s);
    __syncthreads();
    if (t < ROWS) wrow[t] = 1.0 / (16384.0 * v1s[t]);
    __syncthreads();
    {
      double pa = col_partial();
      ++ph; allreduce(ph, false, pa, 0.0, u1_t, dmy);
    }

    // ---- B: v2~, allreduce u2
    alpha[t] = k2_t / u1_t;
    __syncthreads();
    row_pass(v2s);
    __syncthreads();
    if (t < ROWS) wrow[t] = 1.0 / (16384.0 * v2s[t]);
    __syncthreads();
    {
      double pa = col_partial();
      ++ph; allreduce(ph, false, pa, 0.0, u2_t, dmy);
    }

    if (it == 9) {
      // ---- output: Q[b,k] = alpha3[k]*E~[r,k]/v3~[b]
      alpha[t] = k2_t / u2_t;
      __syncthreads();
      row_pass(v3s);
      __syncthreads();
      if (t < ROWS) wrow[t] = 1.0 / v3s[t];
      __syncthreads();
      double a3 = alpha[t];
#pragma unroll 4
      for (int r = 0; r < ROWS; ++r)
        out[(size_t)(b0 + r) * KDIM + t] =
            (float)(a3 * (double)Et[r * KDIM + t] * wrow[r]);
      return;
    }

    // ---- C: v3~, gv3~; allreduce (gdir, t3) pair
    alpha[t] = k2_t / u2_t;
    __syncthreads();
    {
      double a0 = alpha[4 * lane + 0], a1 = alpha[4 * lane + 1];
      double a2 = alpha[4 * lane + 2], a3 = alpha[4 * lane + 3];
#pragma unroll 2
      for (int r = wv; r < ROWS; r += 4) {
        float4 e4 = ((const float4*)(Et + r * KDIM))[lane];
        float4 f4 = ((const float4*)(Ft + r * KDIM))[lane];
        double p0 = a0 * (double)e4.x, p1 = a1 * (double)e4.y;
        double p2 = a2 * (double)e4.z, p3 = a3 * (double)e4.w;
        double s1 = p0 + p1 + p2 + p3;
        double s2 = p0 * (double)f4.x + p1 * (double)f4.y +
                    p2 * (double)f4.z + p3 * (double)f4.w;
        s1 = wave_sum_d(s1);
        s2 = wave_sum_d(s2);
        if (lane == 0) {
          v3s[r] = s1;
          grow[r] = s2 / (16384.0 * s1 * s1);  // gv3~
        }
      }
    }
    __syncthreads();
    if (t < ROWS) wrow[t] = -1.0 / (16384.0 * v3s[t]);
    __syncthreads();
    double gd_t, t3_t;
    {
      double ac1 = 0.0, ac2 = 0.0;
#pragma unroll 8
      for (int r = 0; r < ROWS; ++r) {
        double ed = (double)Et[r * KDIM + t];
        ac1 += ed * (double)Ft[r * KDIM + t] * wrow[r];
        ac2 += ed * grow[r];
      }
      ++ph; allreduce(ph, true, ac1, ac2, gd_t, t3_t);
    }

    // ---- D: gu2 -> gv2~; allreduce ga2
    alpha[t] = -(gd_t + t3_t) * k2_t / (u2_t * u2_t);
    __syncthreads();
    row_pass(grow);
    __syncthreads();
    if (t < ROWS) wrow[t] = -grow[t] / (16384.0 * v2s[t] * v2s[t]);
    __syncthreads();
    double ga2_t;
    {
      double pa = col_partial();
      ++ph; allreduce(ph, false, pa, 0.0, ga2_t, dmy);
    }

    // ---- E: gu1 -> gv1~; allreduce ga1
    alpha[t] = -ga2_t * k2_t / (u1_t * u1_t);
    __syncthreads();
    row_pass(grow);
    __syncthreads();
    if (t < ROWS) wrow[t] = -grow[t] / (16384.0 * v1s[t] * v1s[t]);
    __syncthreads();
    double ga1_t;
    {
      double pa = col_partial();
      ++ph; allreduce(ph, false, pa, 0.0, ga1_t, dmy);
    }

    // ---- F: replicated optimizer step (block-local)
    {
      double gk2 = (gd_t + t3_t) / u2_t + ga2_t / u1_t + ga1_t / u0_t;
      double dot = blk_sum(k2_t * gk2);
      double gw = k2_t * (gk2 - dot) + 5.0 * (k2_t / 256.0 - 1.0 / 65536.0);
      double n2 = blk_sum(gw * gw);
      float normf = (float)sqrt(n2);
      float sc = fminf(1.0f, 1.0f / (normf + 1e-6f));
      float g = (float)gw * sc;
      buf_t = 0.99f * buf_t + g;
      w_t = w_t - 0.1f * buf_t;
      double x = (double)w_t;
      double m = blk_max(x);
      double e = fast_exp_d(x - m);
      double s = blk_sum(e);
      k2_t = e / s;
    }
  }
}

// ---------------------------------------------------------------------------
extern "C" void kernel_launch(void* const* d_in, const int* in_sizes, int n_in,
                              void* d_out, int out_size, void* d_ws,
                              size_t ws_size, hipStream_t stream) {
  (void)in_sizes; (void)n_in; (void)out_size; (void)ws_size;
  const float* feat = (const float*)d_in[0];
  const float* w_in = (const float*)d_in[1];
  float* out = (float*)d_out;
  double* ws = (double*)d_ws;

  kInitWS<<<128, 256, 0, stream>>>(ws);
  sink_main<<<NBLK, 256, 0, stream>>>(feat, w_in, out, ws);
}

// Round 2
// 659.448 us; speedup vs baseline: 1.5432x; 1.5432x over previous
//
#include <hip/hip_runtime.h>

// Balanced sinkhorn, persistent kernel, round 7.
// R6 post-mortem: single-slot fp64 atomics serialize 256 same-address RMWs
// at the coherence point (~74ns each => ~19us/allreduce, 2x WORSE than R5's
// tree). Lesson: keep per-address depth ~1, keep legs parallel across k.
// R7: reduce-scatter + all-gather with per-k block ownership, value-poll
// only (zero flags, zero data atomics):
//   1. block b stores its 256 partials to P[par][b][k] (coalesced 2KB)
//   2. block k owns column k: 256 threads value-poll P[par][r][k] (qNaN
//      sentinel), restore NaN, wave+LDS reduce  (~0.3us)
//   3. result replicated x16 into per-phase res[48][16][256] (fresh, no
//      sentinel recycling)
//   4. all blocks value-poll res[ph][bid&15][t]
// Sentinel-restore ordering: restore is vmcnt-acked at the __syncthreads()
// BEFORE the res store issues; any re-publish to that P slot (phase+2, same
// parity) transitively depends on that res value (R5-validated reasoning).
// Also: phase C's (gd,t3) pair is only ever consumed as gd+t3 -> reduce the
// sum as a single value (halves P, all phases single-value).
// Phase math / LDS tiles / replicated optimizer identical to R3-R6
// (validated, absmax 2.4e-4).

namespace {

constexpr int KDIM = 256;
constexpr int NBLK = 256;   // 1 block/CU, all co-resident (LDS-forced)
constexpr int ROWS = 64;    // rows per block
constexpr int NREP = 16;    // result replicas (16 blocks/line fan-in)
constexpr int NPH  = 48;    // 1 + 9*5 + 2 allreduce phases
constexpr float L2E20 = 28.853900817779268f;  // 20 * log2(e)

// ws layout (doubles):
//   P[2][256 row=blk][256 k]     131072 dbl (1 MB), parity-reused, reader-restored
//   res[48 ph][16 rep][256 k]    196608 dbl (1.5 MB), per-phase fresh
constexpr size_t P_DBL   = 2ull * NBLK * KDIM;          // 131072
constexpr size_t RES_OFF = P_DBL;
constexpr size_t RES_DBL = (size_t)NPH * NREP * KDIM;   // 196608
constexpr size_t WS_DBL  = P_DBL + RES_DBL;             // 327680 (2.62 MB)

__device__ __forceinline__ double fast_exp_d(double x) {
  const double LOG2E  = 1.4426950408889634074;
  const double LN2_HI = 6.93147180369123816490e-01;
  const double LN2_LO = 1.90821492927058770002e-10;
  double n = rint(x * LOG2E);
  double t = fma(-n, LN2_HI, x);
  t = fma(-n, LN2_LO, t);
  double p = 2.4801587301587302e-05;
  p = fma(p, t, 1.9841269841269841e-04);
  p = fma(p, t, 1.3888888888888889e-03);
  p = fma(p, t, 8.3333333333333333e-03);
  p = fma(p, t, 4.1666666666666664e-02);
  p = fma(p, t, 1.6666666666666666e-01);
  p = fma(p, t, 0.5);
  p = fma(p, t, 1.0);
  p = fma(p, t, 1.0);
  long long ni = (long long)n;
  double s = __longlong_as_double((unsigned long long)(ni + 1023LL) << 52);
  return p * s;
}

__device__ __forceinline__ double wave_sum_d(double v) {
#pragma unroll
  for (int o = 32; o > 0; o >>= 1) v += __shfl_down(v, o);
  return v;
}
__device__ __forceinline__ double wave_max_d(double v) {
#pragma unroll
  for (int o = 32; o > 0; o >>= 1) v = fmax(v, __shfl_down(v, o));
  return v;
}

__device__ __forceinline__ double pload(const double* p) {
  return __hip_atomic_load(p, __ATOMIC_RELAXED, __HIP_MEMORY_SCOPE_AGENT);
}
__device__ __forceinline__ void pstore(double* p, double v) {
  __hip_atomic_store(p, v, __ATOMIC_RELAXED, __HIP_MEMORY_SCOPE_AGENT);
}

}  // namespace

// ---------------------------------------------------------------------------
__global__ __launch_bounds__(256) void kInitWS(double* __restrict__ ws) {
  const double QN = __builtin_nan("");
  size_t gid = (size_t)blockIdx.x * 256 + threadIdx.x;
  size_t stride = (size_t)gridDim.x * 256;
  for (size_t j = gid; j < WS_DBL; j += stride) ws[j] = QN;
}

// ---------------------------------------------------------------------------
__global__ __launch_bounds__(256, 1) void sink_main(
    const float* __restrict__ feat, const float* __restrict__ w_in,
    float* __restrict__ out, double* __restrict__ ws) {
  __shared__ float  Et[ROWS * KDIM];   // 64 KB
  __shared__ float  Ft[ROWS * KDIM];   // 64 KB
  __shared__ double alpha[KDIM];
  __shared__ double v1s[ROWS], v2s[ROWS], v3s[ROWS];
  __shared__ double grow[ROWS], wrow[ROWS], sbr[ROWS];
  __shared__ float  mrow[ROWS];
  __shared__ double sred[8];

  const int t = threadIdx.x, bid = blockIdx.x;
  const int wv = t >> 6, lane = t & 63;
  const int b0 = bid * ROWS;
  const double QN = __builtin_nan("");

  double* P   = ws;
  double* res = ws + RES_OFF;

  auto blk_sum = [&](double v) -> double {
    v = wave_sum_d(v);
    __syncthreads();
    if (lane == 0) sred[wv] = v;
    __syncthreads();
    return sred[0] + sred[1] + sred[2] + sred[3];
  };
  auto blk_max = [&](double v) -> double {
    v = wave_max_d(v);
    __syncthreads();
    if (lane == 0) sred[wv + 4] = v;
    __syncthreads();
    return fmax(fmax(sred[4], sred[5]), fmax(sred[6], sred[7]));
  };

  // ---- allreduce over blocks: thread t contributes pa for k=t,
  // returns the 256-block sum for k=t.
  auto allreduce = [&](unsigned ph, double pa) -> double {
    const int p = ph & 1;
    // 1. publish own row (coalesced 2 KB)
    pstore(P + ((size_t)p * NBLK + bid) * KDIM + t, pa);
    // 2. stage-1: this block owns column k=bid; thread t polls row t
    double* e = P + ((size_t)p * NBLK + t) * KDIM + bid;
    double v;
    for (;;) {
      v = pload(e);
      if (!__builtin_isnan(v)) break;
      __builtin_amdgcn_s_sleep(1);
    }
    pstore(e, QN);  // restore sentinel for phase ph+2 (same parity)
    v = wave_sum_d(v);
    __syncthreads();  // vmcnt(0) drain: restores + publish ack'd at L3
    if (lane == 0) sred[wv] = v;
    __syncthreads();
    double s = sred[0] + sred[1] + sred[2] + sred[3];
    // 3. replicate result x16 into the per-phase res slab
    if (t < NREP) pstore(res + ((size_t)ph * NREP + t) * KDIM + bid, s);
    // 4. consume own replica entry
    const double* re = res + ((size_t)ph * NREP + (bid & (NREP - 1))) * KDIM + t;
    double r;
    for (;;) {
      r = pload(re);
      if (!__builtin_isnan(r)) break;
      __builtin_amdgcn_s_sleep(1);
    }
    return r;
  };

  auto row_pass = [&](double* dstv) {
    double a0 = alpha[4 * lane + 0], a1 = alpha[4 * lane + 1];
    double a2 = alpha[4 * lane + 2], a3 = alpha[4 * lane + 3];
#pragma unroll 4
    for (int r = wv; r < ROWS; r += 4) {
      float4 e4 = ((const float4*)(Et + r * KDIM))[lane];
      double s1 = a0 * (double)e4.x + a1 * (double)e4.y +
                  a2 * (double)e4.z + a3 * (double)e4.w;
      s1 = wave_sum_d(s1);
      if (lane == 0) dstv[r] = s1;
    }
  };
  auto col_partial = [&]() -> double {
    double a = 0.0;
#pragma unroll 8
    for (int r = 0; r < ROWS; ++r) a += (double)Et[r * KDIM + t] * wrow[r];
    return a;
  };

  // ================= setup =================
  {
    const float4* src = (const float4*)(feat + (size_t)b0 * KDIM);
    float4* dst = (float4*)Ft;
#pragma unroll
    for (int s = 0; s < 16; ++s) dst[s * 256 + t] = src[s * 256 + t];
  }
  __syncthreads();
  for (int r = wv; r < ROWS; r += 4) {
    float4 f4 = ((const float4*)(Ft + r * KDIM))[lane];
    float m = fmaxf(fmaxf(f4.x, f4.y), fmaxf(f4.z, f4.w));
#pragma unroll
    for (int o = 32; o > 0; o >>= 1) m = fmaxf(m, __shfl_down(m, o));
    if (lane == 0) {
      mrow[r] = m;
      sbr[r] = fast_exp_d(20.0 * (double)m);
    }
  }
  __syncthreads();
  double pu0 = 0.0;
#pragma unroll 8
  for (int r = 0; r < ROWS; ++r) {
    float e = exp2f((Ft[r * KDIM + t] - mrow[r]) * L2E20);
    Et[r * KDIM + t] = e;
    pu0 += (double)e * sbr[r];
  }
  float w_t = w_in[t], buf_t = 0.0f;
  double k2_t;
  {
    double x = (double)w_t;
    double m = blk_max(x);
    double e = fast_exp_d(x - m);
    double s = blk_sum(e);
    k2_t = e / s;
  }
  unsigned ph = 0;
  double u0_t = allreduce(ph, pu0);

  // ================= outer loop =================
  for (int it = 0; it < 10; ++it) {
    double u1_t, u2_t;

    // ---- A: v1~, allreduce u1
    alpha[t] = k2_t / u0_t;
    __syncthreads();
    row_pass(v1s);
    __syncthreads();
    if (t < ROWS) wrow[t] = 1.0 / (16384.0 * v1s[t]);
    __syncthreads();
    {
      double pa = col_partial();
      ++ph; u1_t = allreduce(ph, pa);
    }

    // ---- B: v2~, allreduce u2
    alpha[t] = k2_t / u1_t;
    __syncthreads();
    row_pass(v2s);
    __syncthreads();
    if (t < ROWS) wrow[t] = 1.0 / (16384.0 * v2s[t]);
    __syncthreads();
    {
      double pa = col_partial();
      ++ph; u2_t = allreduce(ph, pa);
    }

    if (it == 9) {
      // ---- output: Q[b,k] = alpha3[k]*E~[r,k]/v3~[b]
      alpha[t] = k2_t / u2_t;
      __syncthreads();
      row_pass(v3s);
      __syncthreads();
      if (t < ROWS) wrow[t] = 1.0 / v3s[t];
      __syncthreads();
      double a3 = alpha[t];
#pragma unroll 4
      for (int r = 0; r < ROWS; ++r)
        out[(size_t)(b0 + r) * KDIM + t] =
            (float)(a3 * (double)Et[r * KDIM + t] * wrow[r]);
      return;
    }

    // ---- C: v3~, gv3~; allreduce gsum = (gdir + t3)  [only the sum is used]
    alpha[t] = k2_t / u2_t;
    __syncthreads();
    {
      double a0 = alpha[4 * lane + 0], a1 = alpha[4 * lane + 1];
      double a2 = alpha[4 * lane + 2], a3 = alpha[4 * lane + 3];
#pragma unroll 2
      for (int r = wv; r < ROWS; r += 4) {
        float4 e4 = ((const float4*)(Et + r * KDIM))[lane];
        float4 f4 = ((const float4*)(Ft + r * KDIM))[lane];
        double p0 = a0 * (double)e4.x, p1 = a1 * (double)e4.y;
        double p2 = a2 * (double)e4.z, p3 = a3 * (double)e4.w;
        double s1 = p0 + p1 + p2 + p3;
        double s2 = p0 * (double)f4.x + p1 * (double)f4.y +
                    p2 * (double)f4.z + p3 * (double)f4.w;
        s1 = wave_sum_d(s1);
        s2 = wave_sum_d(s2);
        if (lane == 0) {
          v3s[r] = s1;
          grow[r] = s2 / (16384.0 * s1 * s1);  // gv3~
        }
      }
    }
    __syncthreads();
    if (t < ROWS) wrow[t] = -1.0 / (16384.0 * v3s[t]);
    __syncthreads();
    double gsum_t;
    {
      double ac1 = 0.0, ac2 = 0.0;
#pragma unroll 8
      for (int r = 0; r < ROWS; ++r) {
        double ed = (double)Et[r * KDIM + t];
        ac1 += ed * (double)Ft[r * KDIM + t] * wrow[r];
        ac2 += ed * grow[r];
      }
      ++ph; gsum_t = allreduce(ph, ac1 + ac2);
    }

    // ---- D: gu2 -> gv2~; allreduce ga2
    alpha[t] = -gsum_t * k2_t / (u2_t * u2_t);
    __syncthreads();
    row_pass(grow);
    __syncthreads();
    if (t < ROWS) wrow[t] = -grow[t] / (16384.0 * v2s[t] * v2s[t]);
    __syncthreads();
    double ga2_t;
    {
      double pa = col_partial();
      ++ph; ga2_t = allreduce(ph, pa);
    }

    // ---- E: gu1 -> gv1~; allreduce ga1
    alpha[t] = -ga2_t * k2_t / (u1_t * u1_t);
    __syncthreads();
    row_pass(grow);
    __syncthreads();
    if (t < ROWS) wrow[t] = -grow[t] / (16384.0 * v1s[t] * v1s[t]);
    __syncthreads();
    double ga1_t;
    {
      double pa = col_partial();
      ++ph; ga1_t = allreduce(ph, pa);
    }

    // ---- F: replicated optimizer step (block-local)
    {
      double gk2 = gsum_t / u2_t + ga2_t / u1_t + ga1_t / u0_t;
      double dot = blk_sum(k2_t * gk2);
      double gw = k2_t * (gk2 - dot) + 5.0 * (k2_t / 256.0 - 1.0 / 65536.0);
      double n2 = blk_sum(gw * gw);
      float normf = (float)sqrt(n2);
      float sc = fminf(1.0f, 1.0f / (normf + 1e-6f));
      float g = (float)gw * sc;
      buf_t = 0.99f * buf_t + g;
      w_t = w_t - 0.1f * buf_t;
      double x = (double)w_t;
      double m = blk_max(x);
      double e = fast_exp_d(x - m);
      double s = blk_sum(e);
      k2_t = e / s;
    }
  }
}

// ---------------------------------------------------------------------------
extern "C" void kernel_launch(void* const* d_in, const int* in_sizes, int n_in,
                              void* d_out, int out_size, void* d_ws,
                              size_t ws_size, hipStream_t stream) {
  (void)in_sizes; (void)n_in; (void)out_size; (void)ws_size;
  const float* feat = (const float*)d_in[0];
  const float* w_in = (const float*)d_in[1];
  float* out = (float*)d_out;
  double* ws = (double*)d_ws;

  kInitWS<<<128, 256, 0, stream>>>(ws);
  sink_main<<<NBLK, 256, 0, stream>>>(feat, w_in, out, ws);
}